// Round 5
// baseline (4841.453 us; speedup 1.0000x reference)
//
#include <hip/hip_runtime.h>

#define NN 200
#define CCH 32
#define OC 64
#define JC 6400     // NN*CCH
#define KF 96       // 3*CCH
#define MC 192      // 3*OC
#define ROWB 51200  // bytes of one out row region [200][64] fp32

__device__ __forceinline__ unsigned short f2bf(float f) {
    unsigned int u = __float_as_uint(f);
    u = (u + 0x7fffu + ((u >> 16) & 1u)) >> 16;   // RNE
    return (unsigned short)u;
}
#define BLO(u) __uint_as_float((u) << 16)
#define BHI(u) __uint_as_float((u) & 0xffff0000u)

// ---------------- prep ----------------
__global__ __launch_bounds__(256) void k_sums(const float* adj, float* cs, float* rs) {
    int t = blockIdx.x * 256 + threadIdx.x;
    if (t < NN) {
        float c = 0.f, r = 0.f;
        for (int p = 0; p < NN; ++p) {
            if (p != t) {
                c += adj[p * NN + t];
                r += adj[t * NN + p];
            }
        }
        cs[t] = c; rs[t] = r;
    }
}

__global__ __launch_bounds__(256) void k_lap(const float* adj, const float* cs, const float* rs,
                                             float* L, float* Lt) {
    int idx = blockIdx.x * 256 + threadIdx.x;
    if (idx < NN * NN) {
        int p = idx / NN, q = idx - p * NN;
        float a = (p == q) ? 0.f : adj[idx];
        float d0 = (cs[p] > 0.f) ? rsqrtf(cs[p]) : 0.f;
        float d1 = (rs[q] > 0.f) ? rsqrtf(rs[q]) : 0.f;
        float v = d0 * a * d1;
        L[idx] = v;             // L[p][q]
        Lt[q * NN + p] = v;     // Lt[e][j] = L[j][e]
    }
}

// C2 = 2*L*L - I ; C2T = transpose(C2)
__global__ __launch_bounds__(256) void k_sq(const float* L, float* C2, float* C2T) {
    int idx = blockIdx.x * 256 + threadIdx.x;
    if (idx < NN * NN) {
        int p = idx / NN, q = idx - p * NN;
        float s = 0.f;
        for (int r = 0; r < NN; ++r) s += L[p * NN + r] * L[r * NN + q];
        float v = 2.f * s - ((p == q) ? 1.f : 0.f);
        C2[idx] = v;
        C2T[q * NN + p] = v;
    }
}

// Wm[k1*32+c][k2*64+o] = w[o][(k1*3+k2)*32+c]   (cols: 0..63 = D, 64..127 = E1, 128..191 = E2)
__global__ __launch_bounds__(256) void k_wprep(const float* w, float* Wm) {
    int idx = blockIdx.x * 256 + threadIdx.x;
    if (idx < KF * MC) {
        int row = idx / MC, col = idx - row * MC;
        int k1 = row >> 5, c = row & 31;
        int k2 = col >> 6, o = col & 63;
        Wm[idx] = w[o * 288 + (k1 * 3 + k2) * 32 + c];
    }
}

// ---------------- stage 1: Y1[t][e][c] = sum_b L[b][i] X[a][b][e][c]; Y2 with C2.
// Staged as bf16 into d_out row region t: Y1 at byte 0 (12800 B), Y2 at byte 12800.
__global__ __launch_bounds__(256)
void k_y(const float* M1, const float* M2, const float* x, char* stag) {
    int a   = blockIdx.z;
    int ib  = blockIdx.y * 32;
    int jc0 = blockIdx.x * 128;
    int tid = threadIdx.x;
    int tx = tid & 31, ty = tid >> 5;   // ty 0..7

    __shared__ float M1s[16][32];
    __shared__ float M2s[16][32];
    __shared__ float Xs[16][128];

    const float* xb = x + (size_t)a * NN * JC;
    float acc1[4][4] = {}, acc2[4][4] = {};

    for (int k0 = 0; k0 < NN; k0 += 16) {
        __syncthreads();
        for (int f = tid; f < 512; f += 256) {
            int bb = f >> 5, ii = f & 31;
            int b = k0 + bb, i = ib + ii;
            float m1 = 0.f, m2 = 0.f;
            if (b < NN && i < NN) { m1 = M1[b * NN + i]; m2 = M2[b * NN + i]; }
            M1s[bb][ii] = m1; M2s[bb][ii] = m2;
        }
        for (int f = tid; f < 2048; f += 256) {
            int bb = f >> 7, jj = f & 127;
            int b = k0 + bb;
            Xs[bb][jj] = (b < NN) ? xb[(size_t)b * JC + jc0 + jj] : 0.f;
        }
        __syncthreads();
        for (int kk = 0; kk < 16; ++kk) {
            float xv[4];
            for (int q = 0; q < 4; ++q) xv[q] = Xs[kk][tx * 4 + q];
            for (int r = 0; r < 4; ++r) {
                float m1 = M1s[kk][ty * 4 + r];
                float m2 = M2s[kk][ty * 4 + r];
                for (int q = 0; q < 4; ++q) {
                    acc1[r][q] += m1 * xv[q];
                    acc2[r][q] += m2 * xv[q];
                }
            }
        }
    }
    for (int r = 0; r < 4; ++r) {
        int i = ib + ty * 4 + r;
        if (i < NN) {
            size_t t = (size_t)a * NN + i;
            char* rowp = stag + t * ROWB;
            size_t boff = (size_t)(jc0 + tx * 4) * 2;
            uint2 p1, p2;
            p1.x = (unsigned)f2bf(acc1[r][0]) | ((unsigned)f2bf(acc1[r][1]) << 16);
            p1.y = (unsigned)f2bf(acc1[r][2]) | ((unsigned)f2bf(acc1[r][3]) << 16);
            p2.x = (unsigned)f2bf(acc2[r][0]) | ((unsigned)f2bf(acc2[r][1]) << 16);
            p2.y = (unsigned)f2bf(acc2[r][2]) | ((unsigned)f2bf(acc2[r][3]) << 16);
            *(uint2*)(rowp + boff) = p1;            // Y1
            *(uint2*)(rowp + 12800 + boff) = p2;    // Y2
        }
    }
}

// ---------------- fused stage 2+3: one block per t = a*200+i.
// Reads Y1[t],Y2[t] bf16 staging (own out row region), X row (input), W (bf16 in LDS),
// B1T/B2T fp32. Accumulates out[j][o] in registers, writes final fp32 row at the end.
__global__ __launch_bounds__(256)
void k_fused(const float* B1T, const float* B2T, const float* Wm, const float* x,
             const float* bias, float* outp) {
    int t = blockIdx.x;
    int a = t / NN, i = t - a * NN;
    int tid = threadIdx.x;

    __shared__ unsigned int Ws2[KF][96];   // bf16 pairs of Wm cols (192 -> 96 pairs)
    __shared__ unsigned int Us2[8][48];    // bf16 pairs of U chunk rows (96 k -> 48 pairs)
    __shared__ float Es[8][MC];            // D|E1|E2 chunk
    __shared__ float B1s[8][208];          // cols 200..207 zero
    __shared__ float B2s[8][208];

    // --- load W to LDS as bf16 pairs
    for (int f = tid; f < KF * 96; f += 256) {
        int k = f / 96, p = f - k * 96;
        float w0 = Wm[k * MC + 2 * p], w1 = Wm[k * MC + 2 * p + 1];
        Ws2[k][p] = (unsigned)f2bf(w0) | ((unsigned)f2bf(w1) << 16);
    }
    for (int f = tid; f < 128; f += 256) {
        int ee = f >> 3, pp = f & 7;
        B1s[ee][200 + pp] = 0.f;
        B2s[ee][200 + pp] = 0.f;
    }

    const float* xrow = x + (size_t)t * JC;
    const char* rowp = (const char*)outp + (size_t)t * ROWB;
    const unsigned int* y1u = (const unsigned int*)rowp;            // [200][16] uints
    const unsigned int* y2u = (const unsigned int*)(rowp + 12800);

    // stage-2 mapping
    int e2 = tid >> 5;            // 0..7
    int ob = (tid & 31) * 6;      // 0..186
    int pb = ob >> 1;
    // stage-3 mapping
    int og = tid >> 4;            // 0..15 -> o = og*4..+3
    int jg = tid & 15;            // j = jg*13 + jj, jj<13

    float acc[13][4] = {};

    for (int e0 = 0; e0 < NN; e0 += 8) {
        __syncthreads();   // protect Es/B/Us of previous chunk
        // load U chunk (X fp32->bf16, Y1/Y2 already bf16)
        for (int f = tid; f < 384; f += 256) {
            int ee = f / 48, p = f - ee * 48;
            int e = e0 + ee;
            unsigned int v;
            if (p < 16) {
                float x0 = xrow[e * CCH + 2 * p];
                float x1 = xrow[e * CCH + 2 * p + 1];
                v = (unsigned)f2bf(x0) | ((unsigned)f2bf(x1) << 16);
            } else if (p < 32) {
                v = y1u[e * 16 + (p - 16)];
            } else {
                v = y2u[e * 16 + (p - 32)];
            }
            Us2[ee][p] = v;
        }
        // load B tiles
        for (int f = tid; f < 1600; f += 256) {
            int ee = f / 200, j = f - ee * 200;
            B1s[ee][j] = B1T[(e0 + ee) * NN + j];
            B2s[ee][j] = B2T[(e0 + ee) * NN + j];
        }
        __syncthreads();

        // --- stage 2: Es[e][col] = sum_k U[e][k] * W[k][col], 6 cols per thread
        {
            float a2[6] = {0.f, 0.f, 0.f, 0.f, 0.f, 0.f};
            for (int kp = 0; kp < 48; ++kp) {
                unsigned uu = Us2[e2][kp];
                float u0 = BLO(uu), u1 = BHI(uu);
                unsigned wa0 = Ws2[2 * kp][pb], wa1 = Ws2[2 * kp][pb + 1], wa2 = Ws2[2 * kp][pb + 2];
                unsigned wb0 = Ws2[2 * kp + 1][pb], wb1 = Ws2[2 * kp + 1][pb + 1], wb2 = Ws2[2 * kp + 1][pb + 2];
                a2[0] += u0 * BLO(wa0) + u1 * BLO(wb0);
                a2[1] += u0 * BHI(wa0) + u1 * BHI(wb0);
                a2[2] += u0 * BLO(wa1) + u1 * BLO(wb1);
                a2[3] += u0 * BHI(wa1) + u1 * BHI(wb1);
                a2[4] += u0 * BLO(wa2) + u1 * BLO(wb2);
                a2[5] += u0 * BHI(wa2) + u1 * BHI(wb2);
            }
            for (int q = 0; q < 6; ++q) Es[e2][ob + q] = a2[q];
        }
        __syncthreads();

        // --- stage 3: accumulate over this e-chunk
        for (int ee = 0; ee < 8; ++ee) {
            float ev1[4], ev2[4];
            for (int q = 0; q < 4; ++q) {
                ev1[q] = Es[ee][64 + og * 4 + q];
                ev2[q] = Es[ee][128 + og * 4 + q];
            }
            for (int jj = 0; jj < 13; ++jj) {
                float b1 = B1s[ee][jg * 13 + jj];
                float b2 = B2s[ee][jg * 13 + jj];
                for (int q = 0; q < 4; ++q)
                    acc[jj][q] += b1 * ev1[q] + b2 * ev2[q];
            }
            // D-term: out[j==e] += D[e][:]
            int el = (e0 + ee) - jg * 13;
            if (el >= 0 && el < 13) {
                for (int q = 0; q < 4; ++q) acc[el][q] += Es[ee][og * 4 + q];
            }
        }
    }

    float bv[4];
    for (int q = 0; q < 4; ++q) bv[q] = bias[og * 4 + q];

    __syncthreads();   // all staging reads done before overwriting own row
    float* orow = outp + (size_t)t * (NN * OC);
    for (int jj = 0; jj < 13; ++jj) {
        int j = jg * 13 + jj;
        if (j < NN) {
            float4 v;
            v.x = acc[jj][0] + bv[0];
            v.y = acc[jj][1] + bv[1];
            v.z = acc[jj][2] + bv[2];
            v.w = acc[jj][3] + bv[3];
            *(float4*)(orow + j * OC + og * 4) = v;
        }
    }
}

extern "C" void kernel_launch(void* const* d_in, const int* in_sizes, int n_in,
                              void* d_out, int out_size, void* d_ws, size_t ws_size,
                              hipStream_t stream) {
    const float* x    = (const float*)d_in[0];   // [8,200,200,32] fp32
    const float* adj  = (const float*)d_in[1];   // [200,200] fp32
    const float* w    = (const float*)d_in[2];   // [64,288] fp32
    const float* bias = (const float*)d_in[3];   // [64] fp32
    float* out = (float*)d_out;                  // [8,200,200,64] fp32

    char* ws = (char*)d_ws;
    size_t off = 0;
    auto alloc = [&](size_t bytes) { size_t p = off; off = (off + bytes + 255) & ~(size_t)255; return p; };
    float* cs  = (float*)(ws + alloc(NN * 4));
    float* rs  = (float*)(ws + alloc(NN * 4));
    float* L   = (float*)(ws + alloc(NN * NN * 4));
    float* Lt  = (float*)(ws + alloc(NN * NN * 4));
    float* C2  = (float*)(ws + alloc(NN * NN * 4));
    float* C2T = (float*)(ws + alloc(NN * NN * 4));
    float* Wm  = (float*)(ws + alloc(KF * MC * 4));
    (void)ws_size;

    k_sums<<<dim3(1), dim3(256), 0, stream>>>(adj, cs, rs);
    k_lap<<<dim3((NN * NN + 255) / 256), dim3(256), 0, stream>>>(adj, cs, rs, L, Lt);
    k_sq<<<dim3((NN * NN + 255) / 256), dim3(256), 0, stream>>>(L, C2, C2T);
    k_wprep<<<dim3((KF * MC + 255) / 256), dim3(256), 0, stream>>>(w, Wm);

    // Stage 1: all batches, Y staged as bf16 inside d_out row regions.
    k_y<<<dim3(50, 7, 8), dim3(256), 0, stream>>>(L, C2, x, (char*)d_out);
    // Fused stage 2+3: one block per (a,i); overwrites its own row with final output.
    k_fused<<<dim3(1600), dim3(256), 0, stream>>>(Lt, C2T, Wm, x, bias, out);
}

// Round 6
// 1869.833 us; speedup vs baseline: 2.5892x; 2.5892x over previous
//
#include <hip/hip_runtime.h>

#define NN 200
#define CCH 32
#define OC 64
#define JC 6400     // NN*CCH
#define KF 96       // 3*CCH
#define MC 192      // 3*OC
#define ROWB 51200  // bytes of one out row region [200][64] fp32

__device__ __forceinline__ unsigned short f2bf(float f) {
    unsigned int u = __float_as_uint(f);
    u = (u + 0x7fffu + ((u >> 16) & 1u)) >> 16;   // RNE
    return (unsigned short)u;
}
#define BLO(u) __uint_as_float((u) << 16)
#define BHI(u) __uint_as_float((u) & 0xffff0000u)

// ---------------- prep ----------------
__global__ __launch_bounds__(256) void k_sums(const float* adj, float* cs, float* rs) {
    int t = blockIdx.x * 256 + threadIdx.x;
    if (t < NN) {
        float c = 0.f, r = 0.f;
        for (int p = 0; p < NN; ++p) {
            if (p != t) {
                c += adj[p * NN + t];
                r += adj[t * NN + p];
            }
        }
        cs[t] = c; rs[t] = r;
    }
}

__global__ __launch_bounds__(256) void k_lap(const float* adj, const float* cs, const float* rs,
                                             float* L, float* Lt) {
    int idx = blockIdx.x * 256 + threadIdx.x;
    if (idx < NN * NN) {
        int p = idx / NN, q = idx - p * NN;
        float a = (p == q) ? 0.f : adj[idx];
        float d0 = (cs[p] > 0.f) ? rsqrtf(cs[p]) : 0.f;
        float d1 = (rs[q] > 0.f) ? rsqrtf(rs[q]) : 0.f;
        float v = d0 * a * d1;
        L[idx] = v;             // L[p][q]
        Lt[q * NN + p] = v;     // Lt[e][j] = L[j][e]
    }
}

// C2 = 2*L*L - I ; C2T = transpose(C2)
__global__ __launch_bounds__(256) void k_sq(const float* L, float* C2, float* C2T) {
    int idx = blockIdx.x * 256 + threadIdx.x;
    if (idx < NN * NN) {
        int p = idx / NN, q = idx - p * NN;
        float s = 0.f;
        for (int r = 0; r < NN; ++r) s += L[p * NN + r] * L[r * NN + q];
        float v = 2.f * s - ((p == q) ? 1.f : 0.f);
        C2[idx] = v;
        C2T[q * NN + p] = v;
    }
}

// Wm[k1*32+c][k2*64+o] = w[o][(k1*3+k2)*32+c]   (cols: 0..63 = D, 64..127 = E1, 128..191 = E2)
__global__ __launch_bounds__(256) void k_wprep(const float* w, float* Wm) {
    int idx = blockIdx.x * 256 + threadIdx.x;
    if (idx < KF * MC) {
        int row = idx / MC, col = idx - row * MC;
        int k1 = row >> 5, c = row & 31;
        int k2 = col >> 6, o = col & 63;
        Wm[idx] = w[o * 288 + (k1 * 3 + k2) * 32 + c];
    }
}

// ---------------- stage 1: Y1[t][e][c] = sum_b L[b][i] X[a][b][e][c]; Y2 with C2.
// Staged as bf16 into d_out row region t: Y1 at byte 0 (12800 B), Y2 at byte 12800.
__global__ __launch_bounds__(256)
void k_y(const float* M1, const float* M2, const float* x, char* stag) {
    int a   = blockIdx.z;
    int ib  = blockIdx.y * 32;
    int jc0 = blockIdx.x * 128;
    int tid = threadIdx.x;
    int tx = tid & 31, ty = tid >> 5;   // ty 0..7

    __shared__ float M1s[16][32];
    __shared__ float M2s[16][32];
    __shared__ float Xs[16][128];

    const float* xb = x + (size_t)a * NN * JC;
    float acc1[4][4] = {}, acc2[4][4] = {};

    for (int k0 = 0; k0 < NN; k0 += 16) {
        __syncthreads();
        for (int f = tid; f < 512; f += 256) {
            int bb = f >> 5, ii = f & 31;
            int b = k0 + bb, i = ib + ii;
            float m1 = 0.f, m2 = 0.f;
            if (b < NN && i < NN) { m1 = M1[b * NN + i]; m2 = M2[b * NN + i]; }
            M1s[bb][ii] = m1; M2s[bb][ii] = m2;
        }
        for (int f = tid; f < 2048; f += 256) {
            int bb = f >> 7, jj = f & 127;
            int b = k0 + bb;
            Xs[bb][jj] = (b < NN) ? xb[(size_t)b * JC + jc0 + jj] : 0.f;
        }
        __syncthreads();
#pragma unroll
        for (int kk = 0; kk < 16; ++kk) {
            float xv[4];
#pragma unroll
            for (int q = 0; q < 4; ++q) xv[q] = Xs[kk][tx * 4 + q];
#pragma unroll
            for (int r = 0; r < 4; ++r) {
                float m1 = M1s[kk][ty * 4 + r];
                float m2 = M2s[kk][ty * 4 + r];
#pragma unroll
                for (int q = 0; q < 4; ++q) {
                    acc1[r][q] += m1 * xv[q];
                    acc2[r][q] += m2 * xv[q];
                }
            }
        }
    }
#pragma unroll
    for (int r = 0; r < 4; ++r) {
        int i = ib + ty * 4 + r;
        if (i < NN) {
            size_t t = (size_t)a * NN + i;
            char* rowp = stag + t * ROWB;
            size_t boff = (size_t)(jc0 + tx * 4) * 2;
            uint2 p1, p2;
            p1.x = (unsigned)f2bf(acc1[r][0]) | ((unsigned)f2bf(acc1[r][1]) << 16);
            p1.y = (unsigned)f2bf(acc1[r][2]) | ((unsigned)f2bf(acc1[r][3]) << 16);
            p2.x = (unsigned)f2bf(acc2[r][0]) | ((unsigned)f2bf(acc2[r][1]) << 16);
            p2.y = (unsigned)f2bf(acc2[r][2]) | ((unsigned)f2bf(acc2[r][3]) << 16);
            *(uint2*)(rowp + boff) = p1;            // Y1
            *(uint2*)(rowp + 12800 + boff) = p2;    // Y2
        }
    }
}

// ---------------- fused stage 2+3: one block per t = a*200+i.
// Staging layout in own out row (51200 B): Y1 [0,12800) bf16, Y2 [12800,25600) bf16,
// D [25600,51200) bf16 (200 e x 64 o x 2B). No dynamic register indexing anywhere.
__global__ __launch_bounds__(256)
void k_fused(const float* B1T, const float* B2T, const float* Wm, const float* x,
             const float* bias, float* outp) {
    int t = blockIdx.x;
    int tid = threadIdx.x;

    __shared__ unsigned int Ws2[KF][96];   // bf16 pairs of Wm cols (192 -> 96 pairs)
    __shared__ unsigned int Us2[8][48];    // bf16 pairs of U chunk rows (96 k -> 48 pairs)
    __shared__ float Es[8][MC];            // D|E1|E2 chunk
    __shared__ float B1s[8][208];          // cols 200..207 zero
    __shared__ float B2s[8][208];

    // --- load W to LDS as bf16 pairs
    for (int f = tid; f < KF * 96; f += 256) {
        int k = f / 96, p = f - k * 96;
        float w0 = Wm[k * MC + 2 * p], w1 = Wm[k * MC + 2 * p + 1];
        Ws2[k][p] = (unsigned)f2bf(w0) | ((unsigned)f2bf(w1) << 16);
    }
    for (int f = tid; f < 128; f += 256) {
        int ee = f >> 3, pp = f & 7;
        B1s[ee][200 + pp] = 0.f;
        B2s[ee][200 + pp] = 0.f;
    }

    const float* xrow = x + (size_t)t * JC;
    char* rowp = (char*)outp + (size_t)t * ROWB;
    const unsigned int* y1u = (const unsigned int*)rowp;            // [200][16] uints
    const unsigned int* y2u = (const unsigned int*)(rowp + 12800);
    unsigned int* dstag = (unsigned int*)(rowp + 25600);            // [200][32] uints (bf16 pairs)

    // stage-2 mapping
    int e2 = tid >> 5;            // 0..7
    int ob = (tid & 31) * 6;      // 0..186
    int pb = ob >> 1;
    // stage-3 mapping
    int og = tid >> 4;            // 0..15 -> o = og*4..+3
    int jg = tid & 15;            // j = jg*13 + jj, jj<13

    float acc[13][4] = {};

    for (int e0 = 0; e0 < NN; e0 += 8) {
        __syncthreads();   // protect Es/B/Us of previous chunk
        // load U chunk (X fp32->bf16, Y1/Y2 already bf16)
        for (int f = tid; f < 384; f += 256) {
            int ee = f / 48, p = f - ee * 48;
            int e = e0 + ee;
            unsigned int v;
            if (p < 16) {
                float x0 = xrow[e * CCH + 2 * p];
                float x1 = xrow[e * CCH + 2 * p + 1];
                v = (unsigned)f2bf(x0) | ((unsigned)f2bf(x1) << 16);
            } else if (p < 32) {
                v = y1u[e * 16 + (p - 16)];
            } else {
                v = y2u[e * 16 + (p - 32)];
            }
            Us2[ee][p] = v;
        }
        // load B tiles
        for (int f = tid; f < 1600; f += 256) {
            int ee = f / 200, j = f - ee * 200;
            B1s[ee][j] = B1T[(e0 + ee) * NN + j];
            B2s[ee][j] = B2T[(e0 + ee) * NN + j];
        }
        __syncthreads();

        // --- stage 2: Es[e][col] = sum_k U[e][k] * W[k][col], 6 cols per thread
        {
            float a2[6] = {0.f, 0.f, 0.f, 0.f, 0.f, 0.f};
#pragma unroll
            for (int kp = 0; kp < 48; ++kp) {
                unsigned uu = Us2[e2][kp];
                float u0 = BLO(uu), u1 = BHI(uu);
                unsigned wa0 = Ws2[2 * kp][pb], wa1 = Ws2[2 * kp][pb + 1], wa2 = Ws2[2 * kp][pb + 2];
                unsigned wb0 = Ws2[2 * kp + 1][pb], wb1 = Ws2[2 * kp + 1][pb + 1], wb2 = Ws2[2 * kp + 1][pb + 2];
                a2[0] += u0 * BLO(wa0) + u1 * BLO(wb0);
                a2[1] += u0 * BHI(wa0) + u1 * BHI(wb0);
                a2[2] += u0 * BLO(wa1) + u1 * BLO(wb1);
                a2[3] += u0 * BHI(wa1) + u1 * BHI(wb1);
                a2[4] += u0 * BLO(wa2) + u1 * BLO(wb2);
                a2[5] += u0 * BHI(wa2) + u1 * BHI(wb2);
            }
#pragma unroll
            for (int q = 0; q < 6; ++q) Es[e2][ob + q] = a2[q];
            // D chunk (cols 0..63) -> global bf16 staging, static indexing
            if (ob < 64) {
#pragma unroll
                for (int p = 0; p < 3; ++p) {
                    int cp = pb + p;   // bf16-pair column
                    if (cp < 32) {
                        dstag[(size_t)(e0 + e2) * 32 + cp] =
                            (unsigned)f2bf(a2[2 * p]) | ((unsigned)f2bf(a2[2 * p + 1]) << 16);
                    }
                }
            }
        }
        __syncthreads();

        // --- stage 3: accumulate over this e-chunk (fully unrolled; acc stays in VGPRs)
#pragma unroll
        for (int ee = 0; ee < 8; ++ee) {
            float ev1[4], ev2[4];
#pragma unroll
            for (int q = 0; q < 4; ++q) {
                ev1[q] = Es[ee][64 + og * 4 + q];
                ev2[q] = Es[ee][128 + og * 4 + q];
            }
#pragma unroll
            for (int jj = 0; jj < 13; ++jj) {
                float b1 = B1s[ee][jg * 13 + jj];
                float b2 = B2s[ee][jg * 13 + jj];
#pragma unroll
                for (int q = 0; q < 4; ++q)
                    acc[jj][q] += b1 * ev1[q] + b2 * ev2[q];
            }
        }
    }

    float bv[4];
#pragma unroll
    for (int q = 0; q < 4; ++q) bv[q] = bias[og * 4 + q];

    // read own D values (j = jg*13+jj, o pair base og*2) before anyone overwrites staging
    __syncthreads();   // drain D stores (vmcnt) + all waves done with chunks
    uint2 dv[13];
#pragma unroll
    for (int jj = 0; jj < 13; ++jj) {
        int j = jg * 13 + jj;
        if (j < NN) dv[jj] = *(const uint2*)&dstag[(size_t)j * 32 + og * 2];
        else { dv[jj].x = 0; dv[jj].y = 0; }
    }
    __syncthreads();   // everyone holds their D regs; now safe to overwrite the row

    float* orow = outp + (size_t)t * (NN * OC);
#pragma unroll
    for (int jj = 0; jj < 13; ++jj) {
        int j = jg * 13 + jj;
        if (j < NN) {
            float4 v;
            v.x = acc[jj][0] + bv[0] + BLO(dv[jj].x);
            v.y = acc[jj][1] + bv[1] + BHI(dv[jj].x);
            v.z = acc[jj][2] + bv[2] + BLO(dv[jj].y);
            v.w = acc[jj][3] + bv[3] + BHI(dv[jj].y);
            *(float4*)(orow + j * OC + og * 4) = v;
        }
    }
}

extern "C" void kernel_launch(void* const* d_in, const int* in_sizes, int n_in,
                              void* d_out, int out_size, void* d_ws, size_t ws_size,
                              hipStream_t stream) {
    const float* x    = (const float*)d_in[0];   // [8,200,200,32] fp32
    const float* adj  = (const float*)d_in[1];   // [200,200] fp32
    const float* w    = (const float*)d_in[2];   // [64,288] fp32
    const float* bias = (const float*)d_in[3];   // [64] fp32
    float* out = (float*)d_out;                  // [8,200,200,64] fp32

    char* ws = (char*)d_ws;
    size_t off = 0;
    auto alloc = [&](size_t bytes) { size_t p = off; off = (off + bytes + 255) & ~(size_t)255; return p; };
    float* cs  = (float*)(ws + alloc(NN * 4));
    float* rs  = (float*)(ws + alloc(NN * 4));
    float* L   = (float*)(ws + alloc(NN * NN * 4));
    float* Lt  = (float*)(ws + alloc(NN * NN * 4));
    float* C2  = (float*)(ws + alloc(NN * NN * 4));
    float* C2T = (float*)(ws + alloc(NN * NN * 4));
    float* Wm  = (float*)(ws + alloc(KF * MC * 4));
    (void)ws_size;

    k_sums<<<dim3(1), dim3(256), 0, stream>>>(adj, cs, rs);
    k_lap<<<dim3((NN * NN + 255) / 256), dim3(256), 0, stream>>>(adj, cs, rs, L, Lt);
    k_sq<<<dim3((NN * NN + 255) / 256), dim3(256), 0, stream>>>(L, C2, C2T);
    k_wprep<<<dim3((KF * MC + 255) / 256), dim3(256), 0, stream>>>(w, Wm);

    // Stage 1: all batches, Y staged as bf16 inside d_out row regions.
    k_y<<<dim3(50, 7, 8), dim3(256), 0, stream>>>(L, C2, x, (char*)d_out);
    // Fused stage 2+3: one block per (a,i); overwrites its own row with final output.
    k_fused<<<dim3(1600), dim3(256), 0, stream>>>(Lt, C2T, Wm, x, bias, out);
}